// Round 5
// baseline (482.397 us; speedup 1.0000x reference)
//
#include <hip/hip_runtime.h>
#include <stdint.h>

// BartAttention fused: out = ((f*exp(QK^T))/rowsum) @ V heads -> @ Wo + bo
// B=2 T=2048 D=1024 H=16 hd=64. Inputs fp32 (established R4), output fp32.
// R5: bf16 prepass (ws-gated) + barrier-free attn with 1024 blocks +
// global_load_lds staging in the GEMMs.

typedef __attribute__((ext_vector_type(8))) short short8;
typedef __attribute__((ext_vector_type(4))) short short4v;
typedef __attribute__((ext_vector_type(4))) float f32x4;
typedef unsigned short u16;

#define T_SEQ 2048
#define NH    16
#define HD    64
#define DM    1024

__device__ __forceinline__ float b2f(u16 h) {
  union { unsigned u; float f; } v; v.u = ((unsigned)h) << 16; return v.f;
}
__device__ __forceinline__ u16 f2bf(float x) {  // round-to-nearest-even
  union { float f; unsigned u; } v; v.f = x;
  unsigned r = v.u + 0x7fffu + ((v.u >> 16) & 1u);
  return (u16)(r >> 16);
}
__device__ __forceinline__ short8 cvt8(const float* p) {
  const f32x4 a = *(const f32x4*)p;
  const f32x4 b = *(const f32x4*)(p + 4);
  short8 o;
  o[0] = (short)f2bf(a[0]); o[1] = (short)f2bf(a[1]);
  o[2] = (short)f2bf(a[2]); o[3] = (short)f2bf(a[3]);
  o[4] = (short)f2bf(b[0]); o[5] = (short)f2bf(b[1]);
  o[6] = (short)f2bf(b[2]); o[7] = (short)f2bf(b[3]);
  return o;
}
__device__ __forceinline__ void gl_lds16(const void* g, void* l) {
  __builtin_amdgcn_global_load_lds(
      (const __attribute__((address_space(1))) void*)g,
      (__attribute__((address_space(3))) void*)l, 16, 0, 0);
}

// ---------------- fp32 -> bf16 prepass ----------------
// Concatenated chunk space (8 elems/chunk): hs | f | Wq | Wk | Wv | Wo
#define HS_CH 524288u
#define F_CH  1048576u
#define W_CH  131072u
__global__ void cvt_kernel(const float* __restrict__ hs, const float* __restrict__ f,
                           const float* __restrict__ Wq, const float* __restrict__ Wk,
                           const float* __restrict__ Wv, const float* __restrict__ Wo,
                           u16* __restrict__ hsb, u16* __restrict__ fb,
                           u16* __restrict__ Wqb, u16* __restrict__ Wkb,
                           u16* __restrict__ Wvb, u16* __restrict__ Wob) {
  unsigned c = blockIdx.x * 256 + threadIdx.x;
  const float* s; u16* d; unsigned off;
  if (c < HS_CH)                       { s = hs; d = hsb; off = c; }
  else if ((c -= HS_CH) < F_CH)        { s = f;  d = fb;  off = c; }
  else if ((c -= F_CH) < W_CH)         { s = Wq; d = Wqb; off = c; }
  else if ((c -= W_CH) < W_CH)         { s = Wk; d = Wkb; off = c; }
  else if ((c -= W_CH) < W_CH)         { s = Wv; d = Wvb; off = c; }
  else                                 { s = Wo; d = Wob; off = c - W_CH; }
  *(short8*)&d[(size_t)off * 8] = cvt8(&s[(size_t)off * 8]);
}

// ---------------- QKV projection GEMM ----------------
// C[m][n] = sum_k X[m][k]*W[n][k] + bias[n]  (128x128, BK=32, k-slab LDS)
// z=0 -> q (x0.125, [B,H,T,hd]); z=1 -> k ([B,H,T,hd]); z=2 -> v ([B,H,hd,T])
__global__ __launch_bounds__(256, 4) void qkv_kernel(
    const void* __restrict__ Xv,
    const void* __restrict__ Wqv, const float* __restrict__ bq,
    const void* __restrict__ Wkv, const float* __restrict__ bk,
    const void* __restrict__ Wvv, const float* __restrict__ bv,
    int isf32,
    u16* __restrict__ q, u16* __restrict__ k, u16* __restrict__ v)
{
  const int z = blockIdx.z;
  const void* Wp = (z == 0) ? Wqv : (z == 1) ? Wkv : Wvv;
  const float* bias = (z == 0) ? bq : (z == 1) ? bk : bv;

  __shared__ alignas(16) short lsA[4][128][8];  // [k-slab][row][8 bf16]
  __shared__ alignas(16) short lsB[4][128][8];

  const int tid = threadIdx.x;
  const int lane = tid & 63;
  const int wv = tid >> 6;
  const int lq = lane >> 4, li = lane & 15;
  const int wm = wv >> 1, wn = wv & 1;

  const int m0 = blockIdx.y * 128;
  const int n0 = blockIdx.x * 128;

  f32x4 acc[4][4];
#pragma unroll
  for (int i = 0; i < 4; i++)
#pragma unroll
    for (int j = 0; j < 4; j++) acc[i][j] = (f32x4){0.f, 0.f, 0.f, 0.f};

  for (int k0 = 0; k0 < DM; k0 += 32) {
    if (isf32) {
      const float* X32 = (const float*)Xv;
      const float* W32 = (const float*)Wp;
#pragma unroll
      for (int r = 0; r < 2; ++r) {
        const int idx = tid + 256 * r;
        const int row = idx >> 2, slab = idx & 3;
        *(short8*)&lsA[slab][row][0] = cvt8(&X32[(size_t)(m0 + row) * DM + k0 + slab * 8]);
        *(short8*)&lsB[slab][row][0] = cvt8(&W32[(size_t)(n0 + row) * DM + k0 + slab * 8]);
      }
    } else {
      const u16* X16 = (const u16*)Xv;
      const u16* W16 = (const u16*)Wp;
#pragma unroll
      for (int r = 0; r < 2; ++r) {
        const int row = r * 64 + lane;   // wave wv stages slab wv, lane-contig LDS
        gl_lds16(&X16[(size_t)(m0 + row) * DM + k0 + wv * 8], &lsA[wv][row][0]);
        gl_lds16(&W16[(size_t)(n0 + row) * DM + k0 + wv * 8], &lsB[wv][row][0]);
      }
    }
    __syncthreads();
    short8 af[4], bf[4];
#pragma unroll
    for (int mt = 0; mt < 4; ++mt)
      af[mt] = *(const short8*)&lsA[lq][wm * 64 + mt * 16 + li][0];
#pragma unroll
    for (int nt = 0; nt < 4; ++nt)
      bf[nt] = *(const short8*)&lsB[lq][wn * 64 + nt * 16 + li][0];
#pragma unroll
    for (int mt = 0; mt < 4; ++mt)
#pragma unroll
      for (int nt = 0; nt < 4; ++nt)
        acc[mt][nt] = __builtin_amdgcn_mfma_f32_16x16x32_bf16(af[mt], bf[nt], acc[mt][nt], 0, 0, 0);
    __syncthreads();
  }

  float bs[4];
#pragma unroll
  for (int nt = 0; nt < 4; ++nt) bs[nt] = bias[n0 + wn * 64 + nt * 16 + li];
  const float scale = (z == 0) ? 0.125f : 1.0f;

  if (z != 2) {
    u16* dst = (z == 0) ? q : k;
#pragma unroll
    for (int mt = 0; mt < 4; ++mt) {
      const int mbase = m0 + wm * 64 + mt * 16 + lq * 4;
#pragma unroll
      for (int nt = 0; nt < 4; ++nt) {
        const int n = n0 + wn * 64 + nt * 16 + li;
        const int h = n >> 6, d = n & 63;
#pragma unroll
        for (int r = 0; r < 4; ++r) {
          const int m = mbase + r;
          const int b = m >> 11, t = m & (T_SEQ - 1);
          dst[((size_t)(b * NH + h) * T_SEQ + t) * HD + d] = f2bf((acc[mt][nt][r] + bs[nt]) * scale);
        }
      }
    }
  } else {  // v transposed [B,H,hd,T]
#pragma unroll
    for (int mt = 0; mt < 4; ++mt) {
      const int mbase = m0 + wm * 64 + mt * 16 + lq * 4;
      const int b = mbase >> 11, t = mbase & (T_SEQ - 1);
#pragma unroll
      for (int nt = 0; nt < 4; ++nt) {
        const int n = n0 + wn * 64 + nt * 16 + li;
        const int h = n >> 6, d = n & 63;
        u16 pk[4];
#pragma unroll
        for (int r = 0; r < 4; ++r) pk[r] = f2bf(acc[mt][nt][r] + bs[nt]);
        *(short4v*)&v[((size_t)(b * NH + h) * HD + d) * T_SEQ + t] = *(const short4v*)pk;
      }
    }
  }
}

// ---------------- fused attention (barrier-free) ----------------
// Block = (b, h, 64 t-rows); 4 waves x 16 t each. pP is WAVE-PRIVATE
// (wave w owns rows [w*16, w*16+16)) -> no __syncthreads anywhere.
__global__ __launch_bounds__(256, 4) void attn_kernel(
    const u16* __restrict__ q, const u16* __restrict__ k,
    const u16* __restrict__ v, const void* __restrict__ fv,
    int isf32, u16* __restrict__ ao)
{
  __shared__ alignas(16) short pP[64][136];

  const int tid = threadIdx.x;
  const int w = tid >> 6;
  const int lane = tid & 63;
  const int lq = lane >> 4, li = lane & 15;

  const int t0 = blockIdx.x * 64;
  const int h = blockIdx.y;
  const int b = blockIdx.z;
  const int tw = t0 + w * 16;          // this wave's t base

  const u16* qh = q + (size_t)(b * NH + h) * T_SEQ * HD;
  const u16* kh = k + (size_t)(b * NH + h) * T_SEQ * HD;
  const u16* vh = v + (size_t)(b * NH + h) * HD * T_SEQ;   // [hd][T]

  short8 qf[2];
#pragma unroll
  for (int kk = 0; kk < 2; ++kk)
    qf[kk] = *(const short8*)&qh[(size_t)(tw + li) * HD + kk * 32 + lq * 8];

  f32x4 oacc[4];
#pragma unroll
  for (int j = 0; j < 4; j++) oacc[j] = (f32x4){0.f, 0.f, 0.f, 0.f};
  float den = 0.f;

  for (int s0 = 0; s0 < T_SEQ; s0 += 128) {
    // prefetch f fragments (bf16-packed) before QK so loads overlap MFMA
    short4v fpk[8];
    if (isf32) {
      const float* fb = (const float*)fv + (size_t)b * T_SEQ * T_SEQ;
#pragma unroll
      for (int mt = 0; mt < 8; ++mt) {
        const f32x4 fr = *(const f32x4*)&fb[(size_t)(tw + li) * T_SEQ + s0 + mt * 16 + lq * 4];
        short4v pk;
        pk[0] = (short)f2bf(fr[0]); pk[1] = (short)f2bf(fr[1]);
        pk[2] = (short)f2bf(fr[2]); pk[3] = (short)f2bf(fr[3]);
        fpk[mt] = pk;
      }
    } else {
      const u16* fb = (const u16*)fv + (size_t)b * T_SEQ * T_SEQ;
#pragma unroll
      for (int mt = 0; mt < 8; ++mt)
        fpk[mt] = *(const short4v*)&fb[(size_t)(tw + li) * T_SEQ + s0 + mt * 16 + lq * 4];
    }

    // S^T = K @ Q^T  (A = K s-rows, B = this wave's 16 t)
    f32x4 sacc[8];
#pragma unroll
    for (int mt = 0; mt < 8; ++mt) sacc[mt] = (f32x4){0.f, 0.f, 0.f, 0.f};
#pragma unroll
    for (int kk = 0; kk < 2; ++kk) {
      short8 kf[8];
#pragma unroll
      for (int mt = 0; mt < 8; ++mt)
        kf[mt] = *(const short8*)&kh[(size_t)(s0 + mt * 16 + li) * HD + kk * 32 + lq * 8];
#pragma unroll
      for (int mt = 0; mt < 8; ++mt)
        sacc[mt] = __builtin_amdgcn_mfma_f32_16x16x32_bf16(kf[mt], qf[kk], sacc[mt], 0, 0, 0);
    }

    // P = f * exp(S) -> wave-private pP rows
#pragma unroll
    for (int mt = 0; mt < 8; ++mt) {
      const int scol = mt * 16 + lq * 4;
      u16 pk[4];
#pragma unroll
      for (int r = 0; r < 4; ++r) {
        const float e = __expf(fminf(sacc[mt][r], 60.0f));
        const float p = b2f((u16)fpk[mt][r]) * e;
        den += p;
        pk[r] = f2bf(p);
      }
      *(short4v*)&pP[w * 16 + li][scol] = *(const short4v*)pk;
    }

    // O += P @ V  (A = P from wave-private LDS, B = V^T direct global)
#pragma unroll
    for (int kk = 0; kk < 4; ++kk) {
      const short8 pf = *(const short8*)&pP[w * 16 + li][kk * 32 + lq * 8];
#pragma unroll
      for (int dn = 0; dn < 4; ++dn) {
        const short8 vf = *(const short8*)&vh[(size_t)(dn * 16 + li) * T_SEQ + s0 + kk * 32 + lq * 8];
        oacc[dn] = __builtin_amdgcn_mfma_f32_16x16x32_bf16(pf, vf, oacc[dn], 0, 0, 0);
      }
    }
  }

  // den: lanes {li, li+16, li+32, li+48} hold disjoint s-partials for t=tw+li
  den += __shfl_xor(den, 16, 64);
  den += __shfl_xor(den, 32, 64);

  // epilogue: oacc row lq*4+r is t = tw + lq*4 + r; den lives at lane (lq*4+r)
#pragma unroll
  for (int r = 0; r < 4; ++r) {
    const float rd = 1.0f / __shfl(den, lq * 4 + r, 64);
    const int t = tw + lq * 4 + r;
#pragma unroll
    for (int dn = 0; dn < 4; ++dn) {
      ao[(size_t)(b * T_SEQ + t) * DM + h * HD + dn * 16 + li] = f2bf(oacc[dn][r] * rd);
    }
  }
}

// ---------------- output projection GEMM (fp32 output) ----------------
__global__ __launch_bounds__(256, 4) void oproj_kernel(
    const u16* __restrict__ A, const void* __restrict__ Wov,
    const float* __restrict__ bo, int isf32, float* __restrict__ out)
{
  __shared__ alignas(16) short lsA[4][128][8];
  __shared__ alignas(16) short lsB[4][128][8];

  const int tid = threadIdx.x;
  const int lane = tid & 63;
  const int wv = tid >> 6;
  const int lq = lane >> 4, li = lane & 15;
  const int wm = wv >> 1, wn = wv & 1;

  const int m0 = blockIdx.y * 128;
  const int n0 = blockIdx.x * 128;

  f32x4 acc[4][4];
#pragma unroll
  for (int i = 0; i < 4; i++)
#pragma unroll
    for (int j = 0; j < 4; j++) acc[i][j] = (f32x4){0.f, 0.f, 0.f, 0.f};

  for (int k0 = 0; k0 < DM; k0 += 32) {
#pragma unroll
    for (int r = 0; r < 2; ++r) {
      const int row = r * 64 + lane;
      gl_lds16(&A[(size_t)(m0 + row) * DM + k0 + wv * 8], &lsA[wv][row][0]);
    }
    if (isf32) {
      const float* W32 = (const float*)Wov;
#pragma unroll
      for (int r = 0; r < 2; ++r) {
        const int idx = tid + 256 * r;
        const int row = idx >> 2, slab = idx & 3;
        *(short8*)&lsB[slab][row][0] = cvt8(&W32[(size_t)(n0 + row) * DM + k0 + slab * 8]);
      }
    } else {
      const u16* W16 = (const u16*)Wov;
#pragma unroll
      for (int r = 0; r < 2; ++r) {
        const int row = r * 64 + lane;
        gl_lds16(&W16[(size_t)(n0 + row) * DM + k0 + wv * 8], &lsB[wv][row][0]);
      }
    }
    __syncthreads();
    short8 af[4], bf[4];
#pragma unroll
    for (int mt = 0; mt < 4; ++mt)
      af[mt] = *(const short8*)&lsA[lq][wm * 64 + mt * 16 + li][0];
#pragma unroll
    for (int nt = 0; nt < 4; ++nt)
      bf[nt] = *(const short8*)&lsB[lq][wn * 64 + nt * 16 + li][0];
#pragma unroll
    for (int mt = 0; mt < 4; ++mt)
#pragma unroll
      for (int nt = 0; nt < 4; ++nt)
        acc[mt][nt] = __builtin_amdgcn_mfma_f32_16x16x32_bf16(af[mt], bf[nt], acc[mt][nt], 0, 0, 0);
    __syncthreads();
  }

  float bs[4];
#pragma unroll
  for (int nt = 0; nt < 4; ++nt) bs[nt] = bo[n0 + wn * 64 + nt * 16 + li];

#pragma unroll
  for (int mt = 0; mt < 4; ++mt) {
    const int mbase = m0 + wm * 64 + mt * 16 + lq * 4;
#pragma unroll
    for (int nt = 0; nt < 4; ++nt) {
      const int n = n0 + wn * 64 + nt * 16 + li;
#pragma unroll
      for (int r = 0; r < 4; ++r)
        out[(size_t)(mbase + r) * DM + n] = acc[mt][nt][r] + bs[nt];
    }
  }
}

extern "C" void kernel_launch(void* const* d_in, const int* in_sizes, int n_in,
                              void* d_out, int out_size, void* d_ws, size_t ws_size,
                              hipStream_t stream) {
  (void)in_sizes; (void)n_in; (void)out_size;
  const float* hs = (const float*)d_in[0];
  const float* fa = (const float*)d_in[1];
  const float* Wq = (const float*)d_in[2];
  const float* bq = (const float*)d_in[3];
  const float* Wk = (const float*)d_in[4];
  const float* bk = (const float*)d_in[5];
  const float* Wv = (const float*)d_in[6];
  const float* bv = (const float*)d_in[7];
  const float* Wo = (const float*)d_in[8];
  const float* bo = (const float*)d_in[9];
  float* out = (float*)d_out;

  // Full layout: fb | hsb | Wqb..Wob | qw kw vw aw  (bf16)
  const size_t NEED = 256 + 2u * (8388608u      /*f*/
                                  + 4194304u    /*hs*/
                                  + 4u * 1048576u /*W*/
                                  + 4u * 4194304u /*q,k,v,aw*/);
  char* base = (char*)d_ws + 256;
  if (ws_size >= NEED) {
    u16* fb  = (u16*)base;
    u16* hsb = fb + 8388608u;
    u16* Wqb = hsb + 4194304u;
    u16* Wkb = Wqb + 1048576u;
    u16* Wvb = Wkb + 1048576u;
    u16* Wob = Wvb + 1048576u;
    u16* qw  = Wob + 1048576u;
    u16* kw  = qw + 4194304u;
    u16* vw  = kw + 4194304u;
    u16* aw  = vw + 4194304u;
    cvt_kernel<<<8192, 256, 0, stream>>>(hs, fa, Wq, Wk, Wv, Wo, hsb, fb, Wqb, Wkb, Wvb, Wob);
    qkv_kernel<<<dim3(8, 32, 3), 256, 0, stream>>>(hsb, Wqb, bq, Wkb, bk, Wvb, bv, 0, qw, kw, vw);
    attn_kernel<<<dim3(32, 16, 2), 256, 0, stream>>>(qw, kw, vw, fb, 0, aw);
    oproj_kernel<<<dim3(8, 32, 1), 256, 0, stream>>>(aw, Wob, bo, 0, out);
  } else {
    // fallback: no prepass, fp32 inputs consumed directly
    u16* qw = (u16*)base;
    u16* kw = qw + 4194304u;
    u16* vw = kw + 4194304u;
    u16* aw = vw + 4194304u;
    qkv_kernel<<<dim3(8, 32, 3), 256, 0, stream>>>(hs, Wq, bq, Wk, bk, Wv, bv, 1, qw, kw, vw);
    attn_kernel<<<dim3(32, 16, 2), 256, 0, stream>>>(qw, kw, vw, fa, 1, aw);
    oproj_kernel<<<dim3(8, 32, 1), 256, 0, stream>>>(aw, Wo, bo, 1, out);
  }
}

// Round 6
// 341.777 us; speedup vs baseline: 1.4114x; 1.4114x over previous
//
#include <hip/hip_runtime.h>
#include <stdint.h>

// BartAttention fused: out = ((f*exp(QK^T))/rowsum) @ V heads -> @ Wo + bo
// B=2 T=2048 D=1024 H=16 hd=64. Inputs fp32, output fp32, intermediates bf16.
// R6: attn rebuilt around cooperative double-buffered global_load_lds staging
// of K/V tiles (XOR-swizzled LDS chunks), 128-t blocks, regs hold kf/vf.

typedef __attribute__((ext_vector_type(8))) short short8;
typedef __attribute__((ext_vector_type(4))) short short4v;
typedef __attribute__((ext_vector_type(4))) float f32x4;
typedef unsigned short u16;

#define T_SEQ 2048
#define NH    16
#define HD    64
#define DM    1024

__device__ __forceinline__ float b2f(u16 h) {
  union { unsigned u; float f; } v; v.u = ((unsigned)h) << 16; return v.f;
}
__device__ __forceinline__ u16 f2bf(float x) {  // round-to-nearest-even
  union { float f; unsigned u; } v; v.f = x;
  unsigned r = v.u + 0x7fffu + ((v.u >> 16) & 1u);
  return (u16)(r >> 16);
}
__device__ __forceinline__ short8 cvt8(const float* p) {
  const f32x4 a = *(const f32x4*)p;
  const f32x4 b = *(const f32x4*)(p + 4);
  short8 o;
  o[0] = (short)f2bf(a[0]); o[1] = (short)f2bf(a[1]);
  o[2] = (short)f2bf(a[2]); o[3] = (short)f2bf(a[3]);
  o[4] = (short)f2bf(b[0]); o[5] = (short)f2bf(b[1]);
  o[6] = (short)f2bf(b[2]); o[7] = (short)f2bf(b[3]);
  return o;
}
__device__ __forceinline__ void gl_lds16(const void* g, void* l) {
  __builtin_amdgcn_global_load_lds(
      (const __attribute__((address_space(1))) void*)g,
      (__attribute__((address_space(3))) void*)l, 16, 0, 0);
}

// ---------------- fp32 -> bf16 prepass ----------------
#define HS_CH 524288u
#define F_CH  1048576u
#define W_CH  131072u
__global__ void cvt_kernel(const float* __restrict__ hs, const float* __restrict__ f,
                           const float* __restrict__ Wq, const float* __restrict__ Wk,
                           const float* __restrict__ Wv, const float* __restrict__ Wo,
                           u16* __restrict__ hsb, u16* __restrict__ fb,
                           u16* __restrict__ Wqb, u16* __restrict__ Wkb,
                           u16* __restrict__ Wvb, u16* __restrict__ Wob) {
  unsigned c = blockIdx.x * 256 + threadIdx.x;
  const float* s; u16* d; unsigned off;
  if (c < HS_CH)                       { s = hs; d = hsb; off = c; }
  else if ((c -= HS_CH) < F_CH)        { s = f;  d = fb;  off = c; }
  else if ((c -= F_CH) < W_CH)         { s = Wq; d = Wqb; off = c; }
  else if ((c -= W_CH) < W_CH)         { s = Wk; d = Wkb; off = c; }
  else if ((c -= W_CH) < W_CH)         { s = Wv; d = Wvb; off = c; }
  else                                 { s = Wo; d = Wob; off = c - W_CH; }
  *(short8*)&d[(size_t)off * 8] = cvt8(&s[(size_t)off * 8]);
}

// ---------------- QKV projection GEMM (unchanged from R5) ----------------
__global__ __launch_bounds__(256, 4) void qkv_kernel(
    const void* __restrict__ Xv,
    const void* __restrict__ Wqv, const float* __restrict__ bq,
    const void* __restrict__ Wkv, const float* __restrict__ bk,
    const void* __restrict__ Wvv, const float* __restrict__ bv,
    int isf32,
    u16* __restrict__ q, u16* __restrict__ k, u16* __restrict__ v)
{
  const int z = blockIdx.z;
  const void* Wp = (z == 0) ? Wqv : (z == 1) ? Wkv : Wvv;
  const float* bias = (z == 0) ? bq : (z == 1) ? bk : bv;

  __shared__ alignas(16) short lsA[4][128][8];
  __shared__ alignas(16) short lsB[4][128][8];

  const int tid = threadIdx.x;
  const int lane = tid & 63;
  const int wv = tid >> 6;
  const int lq = lane >> 4, li = lane & 15;
  const int wm = wv >> 1, wn = wv & 1;

  const int m0 = blockIdx.y * 128;
  const int n0 = blockIdx.x * 128;

  f32x4 acc[4][4];
#pragma unroll
  for (int i = 0; i < 4; i++)
#pragma unroll
    for (int j = 0; j < 4; j++) acc[i][j] = (f32x4){0.f, 0.f, 0.f, 0.f};

  for (int k0 = 0; k0 < DM; k0 += 32) {
    if (isf32) {
      const float* X32 = (const float*)Xv;
      const float* W32 = (const float*)Wp;
#pragma unroll
      for (int r = 0; r < 2; ++r) {
        const int idx = tid + 256 * r;
        const int row = idx >> 2, slab = idx & 3;
        *(short8*)&lsA[slab][row][0] = cvt8(&X32[(size_t)(m0 + row) * DM + k0 + slab * 8]);
        *(short8*)&lsB[slab][row][0] = cvt8(&W32[(size_t)(n0 + row) * DM + k0 + slab * 8]);
      }
    } else {
      const u16* X16 = (const u16*)Xv;
      const u16* W16 = (const u16*)Wp;
#pragma unroll
      for (int r = 0; r < 2; ++r) {
        const int row = r * 64 + lane;
        gl_lds16(&X16[(size_t)(m0 + row) * DM + k0 + wv * 8], &lsA[wv][row][0]);
        gl_lds16(&W16[(size_t)(n0 + row) * DM + k0 + wv * 8], &lsB[wv][row][0]);
      }
    }
    __syncthreads();
    short8 af[4], bf[4];
#pragma unroll
    for (int mt = 0; mt < 4; ++mt)
      af[mt] = *(const short8*)&lsA[lq][wm * 64 + mt * 16 + li][0];
#pragma unroll
    for (int nt = 0; nt < 4; ++nt)
      bf[nt] = *(const short8*)&lsB[lq][wn * 64 + nt * 16 + li][0];
#pragma unroll
    for (int mt = 0; mt < 4; ++mt)
#pragma unroll
      for (int nt = 0; nt < 4; ++nt)
        acc[mt][nt] = __builtin_amdgcn_mfma_f32_16x16x32_bf16(af[mt], bf[nt], acc[mt][nt], 0, 0, 0);
    __syncthreads();
  }

  float bs[4];
#pragma unroll
  for (int nt = 0; nt < 4; ++nt) bs[nt] = bias[n0 + wn * 64 + nt * 16 + li];
  const float scale = (z == 0) ? 0.125f : 1.0f;

  if (z != 2) {
    u16* dst = (z == 0) ? q : k;
#pragma unroll
    for (int mt = 0; mt < 4; ++mt) {
      const int mbase = m0 + wm * 64 + mt * 16 + lq * 4;
#pragma unroll
      for (int nt = 0; nt < 4; ++nt) {
        const int n = n0 + wn * 64 + nt * 16 + li;
        const int h = n >> 6, d = n & 63;
#pragma unroll
        for (int r = 0; r < 4; ++r) {
          const int m = mbase + r;
          const int b = m >> 11, t = m & (T_SEQ - 1);
          dst[((size_t)(b * NH + h) * T_SEQ + t) * HD + d] = f2bf((acc[mt][nt][r] + bs[nt]) * scale);
        }
      }
    }
  } else {
#pragma unroll
    for (int mt = 0; mt < 4; ++mt) {
      const int mbase = m0 + wm * 64 + mt * 16 + lq * 4;
      const int b = mbase >> 11, t = mbase & (T_SEQ - 1);
#pragma unroll
      for (int nt = 0; nt < 4; ++nt) {
        const int n = n0 + wn * 64 + nt * 16 + li;
        const int h = n >> 6, d = n & 63;
        u16 pk[4];
#pragma unroll
        for (int r = 0; r < 4; ++r) pk[r] = f2bf(acc[mt][nt][r] + bs[nt]);
        *(short4v*)&v[((size_t)(b * NH + h) * HD + d) * T_SEQ + t] = *(const short4v*)pk;
      }
    }
  }
}

// ---------------- fused attention (LDS-staged K/V, double-buffered) ----------
// Block = (b, h, 128 t). 4 waves x 32 t (2 groups of 16). Per s-iter (128 s):
// cooperative gl_lds staging of K-tile (128s x 64d) and V^T-tile (64d x 128s)
// into XOR-swizzled LDS chunks; waves hold kf/vf frags in regs; pP wave-private.
__global__ __launch_bounds__(256, 2) void attn_kernel(
    const u16* __restrict__ q, const u16* __restrict__ k,
    const u16* __restrict__ v, const void* __restrict__ fv,
    int isf32, u16* __restrict__ ao)
{
  __shared__ alignas(16) u16 Kl[2][8192];   // 16B chunk c: s=c/8, jx=c%8, j=jx^(s&7)
  __shared__ alignas(16) u16 Vl[2][8192];   // 16B chunk c: d=c/16, scx=c%16, sc=scx^(d&15)
  __shared__ alignas(16) u16 pPf[4][2048];  // per-wave 16t x 128s, 8B chunks ^((li&7)*2)

  const int tid = threadIdx.x;
  const int w = tid >> 6;
  const int lane = tid & 63;
  const int lq = lane >> 4, li = lane & 15;

  const int t0 = blockIdx.x * 128;
  const int h = blockIdx.y;
  const int b = blockIdx.z;

  const u16* qh = q + (size_t)(b * NH + h) * T_SEQ * HD;
  const u16* kh = k + (size_t)(b * NH + h) * T_SEQ * HD;
  const u16* vh = v + (size_t)(b * NH + h) * HD * T_SEQ;   // [hd][T]

  // Q frags for both 16-t groups, kept all kernel
  short8 qf[2][2];
#pragma unroll
  for (int g = 0; g < 2; ++g)
#pragma unroll
    for (int kk = 0; kk < 2; ++kk)
      qf[g][kk] = *(const short8*)&qh[(size_t)(t0 + w * 32 + g * 16 + li) * HD + kk * 32 + lq * 8];

  f32x4 oacc[2][4];
#pragma unroll
  for (int g = 0; g < 2; ++g)
#pragma unroll
    for (int j = 0; j < 4; j++) oacc[g][j] = (f32x4){0.f, 0.f, 0.f, 0.f};
  float den[2] = {0.f, 0.f};

  // ---- staging helper (inlined twice) ----
#define STAGE_TILE(S0, BUF)                                                      \
  {                                                                              \
    const u16* gK = kh + (size_t)(S0) * HD;                                      \
    const u16* gV = vh + (S0);                                                   \
    u16* Kb = &Kl[BUF][0];                                                       \
    u16* Vb = &Vl[BUF][0];                                                       \
    _Pragma("unroll")                                                            \
    for (int r = 0; r < 4; ++r) {                                                \
      const int L = (w * 4 + r) * 64 + lane;                                     \
      const int sl = L >> 3, jx = L & 7, j = jx ^ (sl & 7);                      \
      gl_lds16(gK + (size_t)sl * HD + j * 8, Kb + (size_t)L * 8);                \
      const int d = L >> 4, scx = L & 15, sc = scx ^ (d & 15);                   \
      gl_lds16(gV + (size_t)d * T_SEQ + sc * 8, Vb + (size_t)L * 8);             \
    }                                                                            \
  }

  STAGE_TILE(0, 0)
  __syncthreads();

  for (int it = 0; it < 16; ++it) {
    const int cur = it & 1;
    const int s0 = it * 128;
    if (it < 15) STAGE_TILE(s0 + 128, cur ^ 1)

    const u16* Kb = &Kl[cur][0];
    const u16* Vb = &Vl[cur][0];

    // K frags: whole tile -> regs (each byte read once per wave)
    short8 kf[2][8];
#pragma unroll
    for (int kk = 0; kk < 2; ++kk)
#pragma unroll
      for (int mt = 0; mt < 8; ++mt) {
        const int sl = mt * 16 + li;
        const int c = sl * 8 + ((kk * 4 + lq) ^ (sl & 7));
        kf[kk][mt] = *(const short8*)&Kb[(size_t)c * 8];
      }
    // V frags: whole tile -> regs
    short8 vf[4][4];
#pragma unroll
    for (int kk = 0; kk < 4; ++kk)
#pragma unroll
      for (int dn = 0; dn < 4; ++dn) {
        const int d = dn * 16 + li;
        const int c = d * 16 + ((kk * 4 + lq) ^ (d & 15));
        vf[kk][dn] = *(const short8*)&Vb[(size_t)c * 8];
      }

    u16* pw = &pPf[w][0];
#pragma unroll
    for (int g = 0; g < 2; ++g) {
      // S^T = K @ Q^T for this 16-t group
      f32x4 sacc[8];
#pragma unroll
      for (int mt = 0; mt < 8; ++mt) sacc[mt] = (f32x4){0.f, 0.f, 0.f, 0.f};
#pragma unroll
      for (int kk = 0; kk < 2; ++kk)
#pragma unroll
        for (int mt = 0; mt < 8; ++mt)
          sacc[mt] = __builtin_amdgcn_mfma_f32_16x16x32_bf16(kf[kk][mt], qf[g][kk], sacc[mt], 0, 0, 0);

      // P = f * exp(S) -> wave-private pP (swizzled 8B chunks)
      const int tg = t0 + w * 32 + g * 16 + li;     // this lane's t (col = li)
#pragma unroll
      for (int mt = 0; mt < 8; ++mt) {
        u16 pk[4];
        if (isf32) {
          const float* fb = (const float*)fv + (size_t)b * T_SEQ * T_SEQ;
          const f32x4 fr = *(const f32x4*)&fb[(size_t)tg * T_SEQ + s0 + mt * 16 + lq * 4];
#pragma unroll
          for (int r = 0; r < 4; ++r) {
            const float e = __expf(fminf(sacc[mt][r], 60.0f));
            const float p = fr[r] * e;
            den[g] += p;
            pk[r] = f2bf(p);
          }
        } else {
          const u16* fb = (const u16*)fv + (size_t)b * T_SEQ * T_SEQ;
          const short4v fr = *(const short4v*)&fb[(size_t)tg * T_SEQ + s0 + mt * 16 + lq * 4];
#pragma unroll
          for (int r = 0; r < 4; ++r) {
            const float e = __expf(fminf(sacc[mt][r], 60.0f));
            const float p = b2f((u16)fr[r]) * e;
            den[g] += p;
            pk[r] = f2bf(p);
          }
        }
        const int c8 = (mt * 4 + lq) ^ ((li & 7) << 1);
        *(short4v*)&pw[li * 128 + c8 * 4] = *(const short4v*)pk;
      }

      // O += P @ V
#pragma unroll
      for (int kk = 0; kk < 4; ++kk) {
        const int c8 = ((kk << 3) + (lq << 1)) ^ ((li & 7) << 1);
        const short8 pf = *(const short8*)&pw[li * 128 + c8 * 4];
#pragma unroll
        for (int dn = 0; dn < 4; ++dn)
          oacc[g][dn] = __builtin_amdgcn_mfma_f32_16x16x32_bf16(pf, vf[kk][dn], oacc[g][dn], 0, 0, 0);
      }
    }
    __syncthreads();
  }

  // den reduce: lanes {li, li+16, li+32, li+48} hold disjoint s-partials of t-col li
#pragma unroll
  for (int g = 0; g < 2; ++g) {
    den[g] += __shfl_xor(den[g], 16, 64);
    den[g] += __shfl_xor(den[g], 32, 64);
  }

#pragma unroll
  for (int g = 0; g < 2; ++g) {
#pragma unroll
    for (int r = 0; r < 4; ++r) {
      const float rd = 1.0f / __shfl(den[g], lq * 4 + r, 64);
      const int t = t0 + w * 32 + g * 16 + lq * 4 + r;
#pragma unroll
      for (int dn = 0; dn < 4; ++dn)
        ao[(size_t)(b * T_SEQ + t) * DM + h * HD + dn * 16 + li] = f2bf(oacc[g][dn][r] * rd);
    }
  }
#undef STAGE_TILE
}

// ---------------- output projection GEMM (fp32 output, unchanged) -----------
__global__ __launch_bounds__(256, 4) void oproj_kernel(
    const u16* __restrict__ A, const void* __restrict__ Wov,
    const float* __restrict__ bo, int isf32, float* __restrict__ out)
{
  __shared__ alignas(16) short lsA[4][128][8];
  __shared__ alignas(16) short lsB[4][128][8];

  const int tid = threadIdx.x;
  const int lane = tid & 63;
  const int wv = tid >> 6;
  const int lq = lane >> 4, li = lane & 15;
  const int wm = wv >> 1, wn = wv & 1;

  const int m0 = blockIdx.y * 128;
  const int n0 = blockIdx.x * 128;

  f32x4 acc[4][4];
#pragma unroll
  for (int i = 0; i < 4; i++)
#pragma unroll
    for (int j = 0; j < 4; j++) acc[i][j] = (f32x4){0.f, 0.f, 0.f, 0.f};

  for (int k0 = 0; k0 < DM; k0 += 32) {
#pragma unroll
    for (int r = 0; r < 2; ++r) {
      const int row = r * 64 + lane;
      gl_lds16(&A[(size_t)(m0 + row) * DM + k0 + wv * 8], &lsA[wv][row][0]);
    }
    if (isf32) {
      const float* W32 = (const float*)Wov;
#pragma unroll
      for (int r = 0; r < 2; ++r) {
        const int idx = tid + 256 * r;
        const int row = idx >> 2, slab = idx & 3;
        *(short8*)&lsB[slab][row][0] = cvt8(&W32[(size_t)(n0 + row) * DM + k0 + slab * 8]);
      }
    } else {
      const u16* W16 = (const u16*)Wov;
#pragma unroll
      for (int r = 0; r < 2; ++r) {
        const int row = r * 64 + lane;
        gl_lds16(&W16[(size_t)(n0 + row) * DM + k0 + wv * 8], &lsB[wv][row][0]);
      }
    }
    __syncthreads();
    short8 af[4], bf[4];
#pragma unroll
    for (int mt = 0; mt < 4; ++mt)
      af[mt] = *(const short8*)&lsA[lq][wm * 64 + mt * 16 + li][0];
#pragma unroll
    for (int nt = 0; nt < 4; ++nt)
      bf[nt] = *(const short8*)&lsB[lq][wn * 64 + nt * 16 + li][0];
#pragma unroll
    for (int mt = 0; mt < 4; ++mt)
#pragma unroll
      for (int nt = 0; nt < 4; ++nt)
        acc[mt][nt] = __builtin_amdgcn_mfma_f32_16x16x32_bf16(af[mt], bf[nt], acc[mt][nt], 0, 0, 0);
    __syncthreads();
  }

  float bs[4];
#pragma unroll
  for (int nt = 0; nt < 4; ++nt) bs[nt] = bo[n0 + wn * 64 + nt * 16 + li];

#pragma unroll
  for (int mt = 0; mt < 4; ++mt) {
    const int mbase = m0 + wm * 64 + mt * 16 + lq * 4;
#pragma unroll
    for (int nt = 0; nt < 4; ++nt) {
      const int n = n0 + wn * 64 + nt * 16 + li;
#pragma unroll
      for (int r = 0; r < 4; ++r)
        out[(size_t)(mbase + r) * DM + n] = acc[mt][nt][r] + bs[nt];
    }
  }
}

extern "C" void kernel_launch(void* const* d_in, const int* in_sizes, int n_in,
                              void* d_out, int out_size, void* d_ws, size_t ws_size,
                              hipStream_t stream) {
  (void)in_sizes; (void)n_in; (void)out_size;
  const float* hs = (const float*)d_in[0];
  const float* fa = (const float*)d_in[1];
  const float* Wq = (const float*)d_in[2];
  const float* bq = (const float*)d_in[3];
  const float* Wk = (const float*)d_in[4];
  const float* bk = (const float*)d_in[5];
  const float* Wv = (const float*)d_in[6];
  const float* bv = (const float*)d_in[7];
  const float* Wo = (const float*)d_in[8];
  const float* bo = (const float*)d_in[9];
  float* out = (float*)d_out;

  const size_t NEED = 256 + 2u * (8388608u + 4194304u + 4u * 1048576u + 4u * 4194304u);
  char* base = (char*)d_ws + 256;
  if (ws_size >= NEED) {
    u16* fb  = (u16*)base;
    u16* hsb = fb + 8388608u;
    u16* Wqb = hsb + 4194304u;
    u16* Wkb = Wqb + 1048576u;
    u16* Wvb = Wkb + 1048576u;
    u16* Wob = Wvb + 1048576u;
    u16* qw  = Wob + 1048576u;
    u16* kw  = qw + 4194304u;
    u16* vw  = kw + 4194304u;
    u16* aw  = vw + 4194304u;
    cvt_kernel<<<8192, 256, 0, stream>>>(hs, fa, Wq, Wk, Wv, Wo, hsb, fb, Wqb, Wkb, Wvb, Wob);
    qkv_kernel<<<dim3(8, 32, 3), 256, 0, stream>>>(hsb, Wqb, bq, Wkb, bk, Wvb, bv, 0, qw, kw, vw);
    attn_kernel<<<dim3(16, 16, 2), 256, 0, stream>>>(qw, kw, vw, fb, 0, aw);
    oproj_kernel<<<dim3(8, 32, 1), 256, 0, stream>>>(aw, Wob, bo, 0, out);
  } else {
    u16* qw = (u16*)base;
    u16* kw = qw + 4194304u;
    u16* vw = kw + 4194304u;
    u16* aw = vw + 4194304u;
    qkv_kernel<<<dim3(8, 32, 3), 256, 0, stream>>>(hs, Wq, bq, Wk, bk, Wv, bv, 1, qw, kw, vw);
    attn_kernel<<<dim3(16, 16, 2), 256, 0, stream>>>(qw, kw, vw, fa, 1, aw);
    oproj_kernel<<<dim3(8, 32, 1), 256, 0, stream>>>(aw, Wo, bo, 1, out);
  }
}